// Round 1
// baseline (1150.479 us; speedup 1.0000x reference)
//
#include <hip/hip_runtime.h>
#include <hip/hip_bf16.h>

// ---------------- problem constants ----------------
#define B_TOTAL   32768
#define L_SITES   256
#define N_MID     254        // L-2 middle sites
#define HALF_PI_F 1.57079632679489662f
#define EPS_NORM  1e-8f

// ---------------- ws layout (float slots) ----------------
// [WS_A   .. +520191]  cores_mid fp32, layout [t][f][a][c]  (t<254, f<2, a<32, c<32)
// [WS_C0  .. +63]      core0 fp32  [f][d]
// [WS_CN  .. +639]     coreN fp32  [f][a][c10]
// [WS_X   .. +8388607] x fp32 [B][L]
// [WS_FLAG]            u32 flag: 1 = inputs are bf16, 0 = fp32
// total = 8909505 floats = 35,638,020 bytes (ws_size must cover this)
#define WS_A    0
#define WS_C0   520192
#define WS_CN   520256
#define WS_X    520896
#define WS_FLAG 8909504

#define N_X  8388608
#define N_AM 520192
#define N_C0 64
#define N_CN 640

// ---------------- dtype detector ----------------
// bf16 pairs viewed as u32: low 16 bits are a bf16 in [0,1) -> always < 0x4000.
// fp32 uniform [0,1): low16 bits are mantissa bits, >= 0x4000 with p=0.75 each.
__global__ void detect_dtype(const unsigned int* __restrict__ x_raw,
                             unsigned int* __restrict__ flag) {
    unsigned int v = x_raw[threadIdx.x];          // 64 threads, 256 B read: safe either dtype
    bool big = (v & 0xFFFFu) >= 0x4000u;
    unsigned long long m = __ballot(big);
    if (threadIdx.x == 0) *flag = (m == 0ull) ? 1u : 0u;
}

// ---------------- input conversion to fp32 workspace ----------------
__global__ void convert_inputs(const void* __restrict__ x_in,
                               const void* __restrict__ c0_in,
                               const void* __restrict__ am_in,
                               const void* __restrict__ cn_in,
                               float* __restrict__ ws) {
    const unsigned int bf = *(const unsigned int*)(ws + WS_FLAG);
    const long long i = (long long)blockIdx.x * blockDim.x + threadIdx.x;
    if (i < N_X) {
        float v = bf ? __bfloat162float(((const __hip_bfloat16*)x_in)[i])
                     : ((const float*)x_in)[i];
        ws[WS_X + i] = v;
    }
    if (i < N_AM) {
        float v = bf ? __bfloat162float(((const __hip_bfloat16*)am_in)[i])
                     : ((const float*)am_in)[i];
        ws[WS_A + i] = v;
    }
    if (i < N_C0) {
        float v = bf ? __bfloat162float(((const __hip_bfloat16*)c0_in)[i])
                     : ((const float*)c0_in)[i];
        ws[WS_C0 + i] = v;
    }
    if (i < N_CN) {
        float v = bf ? __bfloat162float(((const __hip_bfloat16*)cn_in)[i])
                     : ((const float*)cn_in)[i];
        ws[WS_CN + i] = v;
    }
}

// ---------------- main chain kernel ----------------
// Block = 128 threads = 2 waves. Wave h in {0,1} handles output columns
// c in [16h, 16h+16) for 64 samples. Grid = 512 blocks -> 32768 samples,
// 1024 waves -> 4 waves/CU (one per SIMD).
// A-matrix accesses are wave-uniform (h via readfirstlane) -> SMEM s_loads.
__global__ __launch_bounds__(128)
void mps_main(const float* __restrict__ ws, void* __restrict__ out) {
    __shared__ float sm[2][64][17];   // +1 pad: conflict-free strided access
    __shared__ float sss[2][64];

    const int lane = threadIdx.x & 63;
    const int h    = __builtin_amdgcn_readfirstlane(threadIdx.x >> 6); // wave-uniform
    const int s    = blockIdx.x * 64 + lane;

    const float* __restrict__ xrow = ws + WS_X + (long long)s * L_SITES;
    const float* __restrict__ A    = ws + WS_A;

    // ---- M0 = cos0*core0[0] + sin0*core0[1] (not normalized, per reference) ----
    float M[32];
    {
        float x0 = xrow[0];
        float sn, cs; __sincosf(HALF_PI_F * x0, &sn, &cs);
        const float* k0 = ws + WS_C0;
        #pragma unroll
        for (int d = 0; d < 32; ++d)
            M[d] = cs * k0[d] + sn * k0[32 + d];
    }

    const int coff = h * 16;

    #pragma unroll 1
    for (int t = 0; t < N_MID; ++t) {
        float xt = xrow[1 + t];
        float st, ct; __sincosf(HALF_PI_F * xt, &st, &ct);

        const float* __restrict__ At = A + t * 2048;   // [f][a][c]
        float y0[16], y1[16];
        #pragma unroll
        for (int j = 0; j < 16; ++j) { y0[j] = 0.f; y1[j] = 0.f; }

        #pragma unroll
        for (int a = 0; a < 32; ++a) {
            const float Ma = M[a];
            const float* __restrict__ r0 = At + a * 32 + coff;        // wave-uniform addr
            const float* __restrict__ r1 = r0 + 1024;
            #pragma unroll
            for (int j = 0; j < 16; ++j) {
                y0[j] = fmaf(Ma, r0[j], y0[j]);
                y1[j] = fmaf(Ma, r1[j], y1[j]);
            }
        }

        // combine features, partial sum of squares, publish half to LDS
        float ssh = 0.f;
        #pragma unroll
        for (int j = 0; j < 16; ++j) {
            float m = ct * y0[j] + st * y1[j];
            ssh = fmaf(m, m, ssh);
            sm[h][lane][j] = m;
        }
        sss[h][lane] = ssh;
        __syncthreads();

        const float ss = sss[0][lane] + sss[1][lane];
        const float k  = 1.0f / (sqrtf(ss) + EPS_NORM);
        #pragma unroll
        for (int a = 0; a < 32; ++a)
            M[a] = sm[a >> 4][lane][a & 15] * k;
        __syncthreads();   // protect LDS before next iteration's writes
    }

    // ---- readout: logits[c] = sum_a M[a]*(cN*coreN[0,a,c] + sN*coreN[1,a,c]) ----
    if (h == 0) {
        float xN = xrow[L_SITES - 1];
        float sN, cN; __sincosf(HALF_PI_F * xN, &sN, &cN);
        const float* kn = ws + WS_CN;   // [f][a][10]
        float acc[10];
        #pragma unroll
        for (int c = 0; c < 10; ++c) acc[c] = 0.f;
        #pragma unroll
        for (int a = 0; a < 32; ++a) {
            const float Ma = M[a];
            #pragma unroll
            for (int c = 0; c < 10; ++c) {
                float fin = cN * kn[a * 10 + c] + sN * kn[320 + a * 10 + c];
                acc[c] = fmaf(Ma, fin, acc[c]);
            }
        }
        const unsigned int bf = *(const unsigned int*)(ws + WS_FLAG);
        if (bf) {
            __hip_bfloat16* o = (__hip_bfloat16*)out;
            #pragma unroll
            for (int c = 0; c < 10; ++c) o[s * 10 + c] = __float2bfloat16(acc[c]);
        } else {
            float* o = (float*)out;
            #pragma unroll
            for (int c = 0; c < 10; ++c) o[s * 10 + c] = acc[c];
        }
    }
}

// ---------------- launch ----------------
extern "C" void kernel_launch(void* const* d_in, const int* in_sizes, int n_in,
                              void* d_out, int out_size, void* d_ws, size_t ws_size,
                              hipStream_t stream) {
    float* ws = (float*)d_ws;
    // 1) detect input dtype (bf16 vs fp32) -> ws flag
    detect_dtype<<<1, 64, 0, stream>>>((const unsigned int*)d_in[0],
                                       (unsigned int*)(ws + WS_FLAG));
    // 2) convert all inputs to fp32 workspace
    convert_inputs<<<N_X / 256, 256, 0, stream>>>(d_in[0], d_in[1], d_in[2], d_in[3], ws);
    // 3) run the chain: 512 blocks x 128 threads (2 waves: c-split halves)
    mps_main<<<B_TOTAL / 64, 128, 0, stream>>>(ws, d_out);
}

// Round 2
// 374.496 us; speedup vs baseline: 3.0721x; 3.0721x over previous
//
#include <hip/hip_runtime.h>
#include <hip/hip_bf16.h>

// ---------------- problem constants ----------------
#define B_TOTAL   32768
#define L_SITES   256
#define N_MID     254        // L-2 middle sites
#define HALF_PI_F 1.57079632679489662f
#define EPS_NORM  1e-8f

// ---------------- ws layout (float/dword slots) ----------------
// [WS_FRAG .. +520191]  B-fragment table: 254 steps x 8 frags x 64 lanes x 4 dwords
//                       frag q = h*4 + kh*2 + p  (h: n-half, kh: k-half/feature, p: 0=hi,1=lo)
// [WS_C0   .. +63]      core0 fp32  [f][32]
// [WS_CN   .. +639]     coreN fp32  [f][a][10]
// [WS_X    .. +8388607] xT fp32 [L][B]  (transposed!)
// [WS_FLAG]             u32 flag: 1 = inputs are bf16, 0 = fp32
#define WS_FRAG 0
#define WS_C0   520192
#define WS_CN   520256
#define WS_X    520896
#define WS_FLAG 8909504

typedef short bf16x8 __attribute__((ext_vector_type(8)));
typedef float f32x4  __attribute__((ext_vector_type(4)));

__device__ __forceinline__ unsigned short f2bf(float f) {
    unsigned u = __builtin_bit_cast(unsigned, f);
    u += 0x7FFFu + ((u >> 16) & 1u);          // RNE
    return (unsigned short)(u >> 16);
}
__device__ __forceinline__ float bf2f(unsigned short h) {
    unsigned u = ((unsigned)h) << 16;
    return __builtin_bit_cast(float, u);
}
__device__ __forceinline__ bf16x8 asbf(uint4 u) {
    return __builtin_bit_cast(bf16x8, u);
}
// split 8 fp32 into hi/lo bf16 fragments (3xBF16 fp32-emulation scheme)
__device__ __forceinline__ void split8(const float* v, bf16x8& hi, bf16x8& lo) {
    #pragma unroll
    for (int j = 0; j < 8; ++j) {
        unsigned short h = f2bf(v[j]);
        hi[j] = (short)h;
        lo[j] = (short)f2bf(v[j] - bf2f(h));
    }
}

// ---------------- dtype detector ----------------
__global__ void detect_dtype(const unsigned int* __restrict__ x_raw,
                             unsigned int* __restrict__ flag) {
    unsigned int v = x_raw[threadIdx.x];
    bool big = (v & 0xFFFFu) >= 0x4000u;
    unsigned long long m = __ballot(big);
    if (threadIdx.x == 0) *flag = (m == 0ull) ? 1u : 0u;
}

// ---------------- small cores -> fp32 ws ----------------
__global__ void conv_small(const void* __restrict__ c0_in,
                           const void* __restrict__ cn_in,
                           float* __restrict__ ws) {
    const unsigned bf = *(const unsigned*)(ws + WS_FLAG);
    int i = threadIdx.x;
    if (i < 64)
        ws[WS_C0 + i] = bf ? bf2f(((const unsigned short*)c0_in)[i])
                           : ((const float*)c0_in)[i];
    if (i < 640)
        ws[WS_CN + i] = bf ? bf2f(((const unsigned short*)cn_in)[i])
                           : ((const float*)cn_in)[i];
}

// ---------------- x transpose: [B][L] -> xT [L][B] fp32 ----------------
__global__ void transpose_x(const void* __restrict__ x_in, float* __restrict__ ws) {
    const unsigned bf = *(const unsigned*)(ws + WS_FLAG);
    __shared__ float tile[64][65];
    const int bb = blockIdx.x * 64;
    const int ll = blockIdx.y * 64;
    #pragma unroll
    for (int k = 0; k < 16; ++k) {
        int idx = threadIdx.x + k * 256;
        int row = idx >> 6, col = idx & 63;
        size_t gi = (size_t)(bb + row) * L_SITES + ll + col;
        float v = bf ? bf2f(((const unsigned short*)x_in)[gi])
                     : ((const float*)x_in)[gi];
        tile[row][col] = v;
    }
    __syncthreads();
    #pragma unroll
    for (int k = 0; k < 16; ++k) {
        int idx = threadIdx.x + k * 256;
        int row = idx >> 6, col = idx & 63;
        ws[WS_X + (size_t)(ll + row) * B_TOTAL + bb + col] = tile[col][row];
    }
}

// ---------------- B-fragment builder ----------------
// For step t, the main kernel's wave loads frag q at dword4 index (t*8+q)*64 + lane.
// Fragment element j (of 8) for lane l: B[k][n] with n = 16h + (l&15),
// k_local = (l>>4)*8 + j; stacked matrix row K = kh*32 + k_local -> feature f=kh,
// a = k_local. Element value: hi (p=0) or lo (p=1) bf16 part of cores_mid[t][f][a][n].
__global__ void build_frags(const void* __restrict__ am_in, float* __restrict__ ws) {
    const unsigned bf = *(const unsigned*)(ws + WS_FLAG);
    int i = blockIdx.x * blockDim.x + threadIdx.x;
    if (i >= N_MID * 8 * 64) return;
    const int lane = i & 63;
    const int q = (i >> 6) & 7;
    const int t = i >> 9;
    const int h  = q >> 2;
    const int kh = (q >> 1) & 1;
    const int p  = q & 1;
    const int n  = h * 16 + (lane & 15);
    const int kb = (lane >> 4) * 8;
    unsigned dw[4];
    #pragma unroll
    for (int d = 0; d < 4; ++d) {
        unsigned e01[2];
        #pragma unroll
        for (int s = 0; s < 2; ++s) {
            int a = kb + 2 * d + s;
            size_t idx = ((size_t)(t * 2 + kh) * 32 + a) * 32 + n;
            float v = bf ? bf2f(((const unsigned short*)am_in)[idx])
                         : ((const float*)am_in)[idx];
            unsigned short hi = f2bf(v);
            unsigned short ev = (p == 0) ? hi : f2bf(v - bf2f(hi));
            e01[s] = ev;
        }
        dw[d] = e01[0] | (e01[1] << 16);
    }
    uint4 o; o.x = dw[0]; o.y = dw[1]; o.z = dw[2]; o.w = dw[3];
    ((uint4*)ws)[(size_t)(t * 8 + q) * 64 + lane] = o;
}

// ---------------- main chain kernel (MFMA, 16 samples per wave) ----------------
// Wave state: mm[j] = M[r][quad*8+j], r = lane&15 (row-major k-slice = A-frag order).
// Step: scaled stacks [ct*M ; st*M] @ [A0;A1] via 3xBF16 split -> C-layout result;
// intra-wave LDS transpose back to row order; normalize; repeat. No __syncthreads:
// DS ops from one wave execute in order, each wave has a private LDS region.
__global__ __launch_bounds__(256)
void mps_mfma(const float* __restrict__ ws, void* __restrict__ out) {
    __shared__ float T[4][528];                 // per-wave 16 rows x stride 33
    const int lane = threadIdx.x & 63;
    const int w    = threadIdx.x >> 6;
    const int r    = lane & 15;
    const int quad = lane >> 4;
    const int b0   = (blockIdx.x * 4 + w) * 16;
    const float* __restrict__ xT = ws + WS_X;
    const uint4* __restrict__ BF = (const uint4*)ws;   // WS_FRAG = 0
    float* __restrict__ Tw = &T[w][0];

    // ---- M0 in row-major k-slice order (not normalized, per reference) ----
    float mm[8];
    {
        float x0 = xT[b0 + r];
        float sn, cs; __sincosf(HALF_PI_F * x0, &sn, &cs);
        const float* c0 = ws + WS_C0;
        #pragma unroll
        for (int j = 0; j < 8; ++j) {
            int a = quad * 8 + j;
            mm[j] = cs * c0[a] + sn * c0[32 + a];
        }
    }

    #pragma unroll 1
    for (int t = 0; t < N_MID; ++t) {
        const uint4* Bt = BF + (size_t)(t * 8) * 64 + lane;
        uint4 q0 = Bt[0];        // h=0 kh=0 hi
        uint4 q1 = Bt[64];       // h=0 kh=0 lo
        uint4 q2 = Bt[128];      // h=0 kh=1 hi
        uint4 q3 = Bt[192];      // h=0 kh=1 lo
        uint4 q4 = Bt[256];      // h=1 kh=0 hi
        uint4 q5 = Bt[320];      // h=1 kh=0 lo
        uint4 q6 = Bt[384];      // h=1 kh=1 hi
        uint4 q7 = Bt[448];      // h=1 kh=1 lo

        float xt = xT[(size_t)(1 + t) * B_TOTAL + b0 + r];
        float st, ct; __sincosf(HALF_PI_F * xt, &st, &ct);

        // scaled stacked A-operand rows: [ct*M ; st*M]
        float s0[8], s1[8];
        #pragma unroll
        for (int j = 0; j < 8; ++j) { s0[j] = ct * mm[j]; s1[j] = st * mm[j]; }
        bf16x8 m0h, m0l, m1h, m1l;
        split8(s0, m0h, m0l);
        split8(s1, m1h, m1l);

        const f32x4 z = {0.f, 0.f, 0.f, 0.f};
        // 4 independent 3-chains (h x kh), then add kh-halves
        f32x4 a00 = __builtin_amdgcn_mfma_f32_16x16x32_bf16(m0h, asbf(q0), z, 0, 0, 0);
        a00 = __builtin_amdgcn_mfma_f32_16x16x32_bf16(m0l, asbf(q0), a00, 0, 0, 0);
        a00 = __builtin_amdgcn_mfma_f32_16x16x32_bf16(m0h, asbf(q1), a00, 0, 0, 0);
        f32x4 a01 = __builtin_amdgcn_mfma_f32_16x16x32_bf16(m1h, asbf(q2), z, 0, 0, 0);
        a01 = __builtin_amdgcn_mfma_f32_16x16x32_bf16(m1l, asbf(q2), a01, 0, 0, 0);
        a01 = __builtin_amdgcn_mfma_f32_16x16x32_bf16(m1h, asbf(q3), a01, 0, 0, 0);
        f32x4 a10 = __builtin_amdgcn_mfma_f32_16x16x32_bf16(m0h, asbf(q4), z, 0, 0, 0);
        a10 = __builtin_amdgcn_mfma_f32_16x16x32_bf16(m0l, asbf(q4), a10, 0, 0, 0);
        a10 = __builtin_amdgcn_mfma_f32_16x16x32_bf16(m0h, asbf(q5), a10, 0, 0, 0);
        f32x4 a11 = __builtin_amdgcn_mfma_f32_16x16x32_bf16(m1h, asbf(q6), z, 0, 0, 0);
        a11 = __builtin_amdgcn_mfma_f32_16x16x32_bf16(m1l, asbf(q6), a11, 0, 0, 0);
        a11 = __builtin_amdgcn_mfma_f32_16x16x32_bf16(m1h, asbf(q7), a11, 0, 0, 0);
        f32x4 y0 = a00 + a01;    // cols 0..15   (c = lane&15)
        f32x4 y1 = a10 + a11;    // cols 16..31

        // C-layout -> row-layout via private-wave LDS transpose.
        // write: row = quad*4+reg, col = 16h + r
        #pragma unroll
        for (int reg = 0; reg < 4; ++reg) {
            Tw[(quad * 4 + reg) * 33 + r]      = y0[reg];
            Tw[(quad * 4 + reg) * 33 + 16 + r] = y1[reg];
        }
        // read: row = r, cols quad*8 + j   (2-way bank aliasing only: free)
        float ss = 0.f;
        #pragma unroll
        for (int j = 0; j < 8; ++j) {
            mm[j] = Tw[r * 33 + quad * 8 + j];
            ss = fmaf(mm[j], mm[j], ss);
        }
        ss += __shfl_xor(ss, 16);
        ss += __shfl_xor(ss, 32);
        float kk = 1.0f / (sqrtf(ss) + EPS_NORM);
        #pragma unroll
        for (int j = 0; j < 8; ++j) mm[j] *= kk;
    }

    // ---- readout: logits[r][c] = sum_a M[r][a]*(cN*KN0[a,c] + sN*KN1[a,c]) ----
    {
        float xN = xT[(size_t)(L_SITES - 1) * B_TOTAL + b0 + r];
        float sN, cN; __sincosf(HALF_PI_F * xN, &sN, &cN);
        const float* kn = ws + WS_CN;        // [f][a][10]
        float acc[10];
        #pragma unroll
        for (int c = 0; c < 10; ++c) acc[c] = 0.f;
        #pragma unroll
        for (int j = 0; j < 8; ++j) {
            int a = quad * 8 + j;
            float Ma = mm[j];
            #pragma unroll
            for (int c = 0; c < 10; ++c) {
                float fin = cN * kn[a * 10 + c] + sN * kn[320 + a * 10 + c];
                acc[c] = fmaf(Ma, fin, acc[c]);
            }
        }
        #pragma unroll
        for (int c = 0; c < 10; ++c) {
            acc[c] += __shfl_xor(acc[c], 16);
            acc[c] += __shfl_xor(acc[c], 32);
        }
        const unsigned bf = *(const unsigned*)(ws + WS_FLAG);
        if (quad == 0) {
            if (bf) {
                __hip_bfloat16* o = (__hip_bfloat16*)out;
                #pragma unroll
                for (int c = 0; c < 10; ++c)
                    o[(size_t)(b0 + r) * 10 + c] = __float2bfloat16(acc[c]);
            } else {
                float* o = (float*)out;
                #pragma unroll
                for (int c = 0; c < 10; ++c)
                    o[(size_t)(b0 + r) * 10 + c] = acc[c];
            }
        }
    }
}

// ---------------- launch ----------------
extern "C" void kernel_launch(void* const* d_in, const int* in_sizes, int n_in,
                              void* d_out, int out_size, void* d_ws, size_t ws_size,
                              hipStream_t stream) {
    float* ws = (float*)d_ws;
    detect_dtype<<<1, 64, 0, stream>>>((const unsigned int*)d_in[0],
                                       (unsigned int*)(ws + WS_FLAG));
    conv_small<<<1, 640, 0, stream>>>(d_in[1], d_in[3], ws);
    transpose_x<<<dim3(512, 4), 256, 0, stream>>>(d_in[0], ws);
    build_frags<<<508, 256, 0, stream>>>(d_in[2], ws);
    // 512 blocks x 4 waves x 16 samples = 32768 samples; 2048 waves = 2 waves/SIMD
    mps_mfma<<<512, 256, 0, stream>>>(ws, d_out);
}

// Round 7
// 366.532 us; speedup vs baseline: 3.1388x; 1.0217x over previous
//
#include <hip/hip_runtime.h>
#include <hip/hip_bf16.h>

// ---------------- problem constants ----------------
#define B_TOTAL   32768
#define L_SITES   256
#define N_MID     254        // L-2 middle sites
#define HALF_PI_F 1.57079632679489662f
#define EPS_NORM  1e-8f

// ---------------- ws layout (float/dword slots) ----------------
// [WS_FRAG .. +520191]  B-fragment table: 254 steps x 8 frags x 64 lanes x 4 dwords
//                       frag q = h*4 + kh*2 + p  (h: n-half, kh: k-half/feature, p: 0=hi,1=lo)
// [WS_C0   .. +63]      core0 fp32  [f][32]
// [WS_CN   .. +639]     coreN fp32  [f][a][10]
// [WS_X    .. +8388607] xT fp32 [L][B]  (transposed!)
// [WS_FLAG]             u32 flag: 1 = inputs are bf16, 0 = fp32
#define WS_FRAG 0
#define WS_C0   520192
#define WS_CN   520256
#define WS_X    520896
#define WS_FLAG 8909504

typedef short bf16x8 __attribute__((ext_vector_type(8)));
typedef float f32x4  __attribute__((ext_vector_type(4)));

__device__ __forceinline__ unsigned short f2bf(float f) {
    unsigned u = __builtin_bit_cast(unsigned, f);
    u += 0x7FFFu + ((u >> 16) & 1u);          // RNE
    return (unsigned short)(u >> 16);
}
__device__ __forceinline__ float bf2f(unsigned short h) {
    unsigned u = ((unsigned)h) << 16;
    return __builtin_bit_cast(float, u);
}
__device__ __forceinline__ bf16x8 asbf(uint4 u) {
    return __builtin_bit_cast(bf16x8, u);
}
// split 8 fp32 into hi/lo bf16 fragments (3xBF16 fp32-emulation scheme)
__device__ __forceinline__ void split8(const float* v, bf16x8& hi, bf16x8& lo) {
    #pragma unroll
    for (int j = 0; j < 8; ++j) {
        unsigned short h = f2bf(v[j]);
        hi[j] = (short)h;
        lo[j] = (short)f2bf(v[j] - bf2f(h));
    }
}

// ---------------- dtype detector ----------------
__global__ void detect_dtype(const unsigned int* __restrict__ x_raw,
                             unsigned int* __restrict__ flag) {
    unsigned int v = x_raw[threadIdx.x];
    bool big = (v & 0xFFFFu) >= 0x4000u;
    unsigned long long m = __ballot(big);
    if (threadIdx.x == 0) *flag = (m == 0ull) ? 1u : 0u;
}

// ---------------- small cores -> fp32 ws ----------------
__global__ void conv_small(const void* __restrict__ c0_in,
                           const void* __restrict__ cn_in,
                           float* __restrict__ ws) {
    const unsigned bf = *(const unsigned*)(ws + WS_FLAG);
    int i = threadIdx.x;
    if (i < 64)
        ws[WS_C0 + i] = bf ? bf2f(((const unsigned short*)c0_in)[i])
                           : ((const float*)c0_in)[i];
    if (i < 640)
        ws[WS_CN + i] = bf ? bf2f(((const unsigned short*)cn_in)[i])
                           : ((const float*)cn_in)[i];
}

// ---------------- x transpose: [B][L] -> xT [L][B] fp32 ----------------
__global__ void transpose_x(const void* __restrict__ x_in, float* __restrict__ ws) {
    const unsigned bf = *(const unsigned*)(ws + WS_FLAG);
    __shared__ float tile[64][65];
    const int bb = blockIdx.x * 64;
    const int ll = blockIdx.y * 64;
    #pragma unroll
    for (int k = 0; k < 16; ++k) {
        int idx = threadIdx.x + k * 256;
        int row = idx >> 6, col = idx & 63;
        size_t gi = (size_t)(bb + row) * L_SITES + ll + col;
        float v = bf ? bf2f(((const unsigned short*)x_in)[gi])
                     : ((const float*)x_in)[gi];
        tile[row][col] = v;
    }
    __syncthreads();
    #pragma unroll
    for (int k = 0; k < 16; ++k) {
        int idx = threadIdx.x + k * 256;
        int row = idx >> 6, col = idx & 63;
        ws[WS_X + (size_t)(ll + row) * B_TOTAL + bb + col] = tile[col][row];
    }
}

// ---------------- B-fragment builder ----------------
// For step t, the main kernel's wave loads frag q at dword4 index (t*8+q)*64 + lane.
// Fragment element j (of 8) for lane l: B[k][n] with n = 16h + (l&15),
// k_local = (l>>4)*8 + j; stacked matrix row K = kh*32 + k_local -> feature f=kh,
// a = k_local. Element value: hi (p=0) or lo (p=1) bf16 part of cores_mid[t][f][a][n].
__global__ void build_frags(const void* __restrict__ am_in, float* __restrict__ ws) {
    const unsigned bf = *(const unsigned*)(ws + WS_FLAG);
    int i = blockIdx.x * blockDim.x + threadIdx.x;
    if (i >= N_MID * 8 * 64) return;
    const int lane = i & 63;
    const int q = (i >> 6) & 7;
    const int t = i >> 9;
    const int h  = q >> 2;
    const int kh = (q >> 1) & 1;
    const int p  = q & 1;
    const int n  = h * 16 + (lane & 15);
    const int kb = (lane >> 4) * 8;
    unsigned dw[4];
    #pragma unroll
    for (int d = 0; d < 4; ++d) {
        unsigned e01[2];
        #pragma unroll
        for (int s = 0; s < 2; ++s) {
            int a = kb + 2 * d + s;
            size_t idx = ((size_t)(t * 2 + kh) * 32 + a) * 32 + n;
            float v = bf ? bf2f(((const unsigned short*)am_in)[idx])
                         : ((const float*)am_in)[idx];
            unsigned short hi = f2bf(v);
            unsigned short ev = (p == 0) ? hi : f2bf(v - bf2f(hi));
            e01[s] = ev;
        }
        dw[d] = e01[0] | (e01[1] << 16);
    }
    uint4 o; o.x = dw[0]; o.y = dw[1]; o.z = dw[2]; o.w = dw[3];
    ((uint4*)ws)[(size_t)(t * 8 + q) * 64 + lane] = o;
}

// ---------------- main chain kernel (MFMA, 16 samples per wave) ----------------
// Wave state: mm[j] = M[r][quad*8+j], r = lane&15 (row-major k-slice = A-frag order).
// Step: scaled stacks [ct*M ; st*M] @ [A0;A1] via 3xBF16 split -> C-layout result;
// intra-wave LDS transpose back to row order; normalize; repeat. No __syncthreads:
// DS ops from one wave execute in order, each wave has a private LDS region.
__global__ __launch_bounds__(256)
void mps_mfma(const float* __restrict__ ws, void* __restrict__ out) {
    __shared__ float T[4][528];                 // per-wave 16 rows x stride 33
    const int lane = threadIdx.x & 63;
    const int w    = threadIdx.x >> 6;
    const int r    = lane & 15;
    const int quad = lane >> 4;
    const int b0   = (blockIdx.x * 4 + w) * 16;
    const float* __restrict__ xT = ws + WS_X;
    const uint4* __restrict__ BF = (const uint4*)ws;   // WS_FRAG = 0
    float* __restrict__ Tw = &T[w][0];

    // ---- M0 in row-major k-slice order (not normalized, per reference) ----
    float mm[8];
    {
        float x0 = xT[b0 + r];
        float sn, cs; __sincosf(HALF_PI_F * x0, &sn, &cs);
        const float* c0 = ws + WS_C0;
        #pragma unroll
        for (int j = 0; j < 8; ++j) {
            int a = quad * 8 + j;
            mm[j] = cs * c0[a] + sn * c0[32 + a];
        }
    }

    #pragma unroll 1
    for (int t = 0; t < N_MID; ++t) {
        const uint4* Bt = BF + (size_t)(t * 8) * 64 + lane;
        uint4 q0 = Bt[0];        // h=0 kh=0 hi
        uint4 q1 = Bt[64];       // h=0 kh=0 lo
        uint4 q2 = Bt[128];      // h=0 kh=1 hi
        uint4 q3 = Bt[192];      // h=0 kh=1 lo
        uint4 q4 = Bt[256];      // h=1 kh=0 hi
        uint4 q5 = Bt[320];      // h=1 kh=0 lo
        uint4 q6 = Bt[384];      // h=1 kh=1 hi
        uint4 q7 = Bt[448];      // h=1 kh=1 lo

        float xt = xT[(size_t)(1 + t) * B_TOTAL + b0 + r];
        float st, ct; __sincosf(HALF_PI_F * xt, &st, &ct);

        // scaled stacked A-operand rows: [ct*M ; st*M]
        float s0[8], s1[8];
        #pragma unroll
        for (int j = 0; j < 8; ++j) { s0[j] = ct * mm[j]; s1[j] = st * mm[j]; }
        bf16x8 m0h, m0l, m1h, m1l;
        split8(s0, m0h, m0l);
        split8(s1, m1h, m1l);

        const f32x4 z = {0.f, 0.f, 0.f, 0.f};
        // 4 independent 3-chains (h x kh), then add kh-halves
        f32x4 a00 = __builtin_amdgcn_mfma_f32_16x16x32_bf16(m0h, asbf(q0), z, 0, 0, 0);
        a00 = __builtin_amdgcn_mfma_f32_16x16x32_bf16(m0l, asbf(q0), a00, 0, 0, 0);
        a00 = __builtin_amdgcn_mfma_f32_16x16x32_bf16(m0h, asbf(q1), a00, 0, 0, 0);
        f32x4 a01 = __builtin_amdgcn_mfma_f32_16x16x32_bf16(m1h, asbf(q2), z, 0, 0, 0);
        a01 = __builtin_amdgcn_mfma_f32_16x16x32_bf16(m1l, asbf(q2), a01, 0, 0, 0);
        a01 = __builtin_amdgcn_mfma_f32_16x16x32_bf16(m1h, asbf(q3), a01, 0, 0, 0);
        f32x4 a10 = __builtin_amdgcn_mfma_f32_16x16x32_bf16(m0h, asbf(q4), z, 0, 0, 0);
        a10 = __builtin_amdgcn_mfma_f32_16x16x32_bf16(m0l, asbf(q4), a10, 0, 0, 0);
        a10 = __builtin_amdgcn_mfma_f32_16x16x32_bf16(m0h, asbf(q5), a10, 0, 0, 0);
        f32x4 a11 = __builtin_amdgcn_mfma_f32_16x16x32_bf16(m1h, asbf(q6), z, 0, 0, 0);
        a11 = __builtin_amdgcn_mfma_f32_16x16x32_bf16(m1l, asbf(q6), a11, 0, 0, 0);
        a11 = __builtin_amdgcn_mfma_f32_16x16x32_bf16(m1h, asbf(q7), a11, 0, 0, 0);
        f32x4 y0 = a00 + a01;    // cols 0..15   (c = lane&15)
        f32x4 y1 = a10 + a11;    // cols 16..31

        // C-layout -> row-layout via private-wave LDS transpose.
        // write: row = quad*4+reg, col = 16h + r
        #pragma unroll
        for (int reg = 0; reg < 4; ++reg) {
            Tw[(quad * 4 + reg) * 33 + r]      = y0[reg];
            Tw[(quad * 4 + reg) * 33 + 16 + r] = y1[reg];
        }
        // read: row = r, cols quad*8 + j   (2-way bank aliasing only: free)
        float ss = 0.f;
        #pragma unroll
        for (int j = 0; j < 8; ++j) {
            mm[j] = Tw[r * 33 + quad * 8 + j];
            ss = fmaf(mm[j], mm[j], ss);
        }
        ss += __shfl_xor(ss, 16);
        ss += __shfl_xor(ss, 32);
        float kk = 1.0f / (sqrtf(ss) + EPS_NORM);
        #pragma unroll
        for (int j = 0; j < 8; ++j) mm[j] *= kk;
    }

    // ---- readout: logits[r][c] = sum_a M[r][a]*(cN*KN0[a,c] + sN*KN1[a,c]) ----
    {
        float xN = xT[(size_t)(L_SITES - 1) * B_TOTAL + b0 + r];
        float sN, cN; __sincosf(HALF_PI_F * xN, &sN, &cN);
        const float* kn = ws + WS_CN;        // [f][a][10]
        float acc[10];
        #pragma unroll
        for (int c = 0; c < 10; ++c) acc[c] = 0.f;
        #pragma unroll
        for (int j = 0; j < 8; ++j) {
            int a = quad * 8 + j;
            float Ma = mm[j];
            #pragma unroll
            for (int c = 0; c < 10; ++c) {
                float fin = cN * kn[a * 10 + c] + sN * kn[320 + a * 10 + c];
                acc[c] = fmaf(Ma, fin, acc[c]);
            }
        }
        #pragma unroll
        for (int c = 0; c < 10; ++c) {
            acc[c] += __shfl_xor(acc[c], 16);
            acc[c] += __shfl_xor(acc[c], 32);
        }
        const unsigned bf = *(const unsigned*)(ws + WS_FLAG);
        if (quad == 0) {
            if (bf) {
                __hip_bfloat16* o = (__hip_bfloat16*)out;
                #pragma unroll
                for (int c = 0; c < 10; ++c)
                    o[(size_t)(b0 + r) * 10 + c] = __float2bfloat16(acc[c]);
            } else {
                float* o = (float*)out;
                #pragma unroll
                for (int c = 0; c < 10; ++c)
                    o[(size_t)(b0 + r) * 10 + c] = acc[c];
            }
        }
    }
}

// ---------------- launch ----------------
extern "C" void kernel_launch(void* const* d_in, const int* in_sizes, int n_in,
                              void* d_out, int out_size, void* d_ws, size_t ws_size,
                              hipStream_t stream) {
    float* ws = (float*)d_ws;
    detect_dtype<<<1, 64, 0, stream>>>((const unsigned int*)d_in[0],
                                       (unsigned int*)(ws + WS_FLAG));
    conv_small<<<1, 640, 0, stream>>>(d_in[1], d_in[3], ws);
    transpose_x<<<dim3(512, 4), 256, 0, stream>>>(d_in[0], ws);
    build_frags<<<508, 256, 0, stream>>>(d_in[2], ws);
    // 512 blocks x 4 waves x 16 samples = 32768 samples; 2048 waves = 2 waves/SIMD
    mps_mfma<<<512, 256, 0, stream>>>(ws, d_out);
}

// Round 8
// 284.843 us; speedup vs baseline: 4.0390x; 1.2868x over previous
//
#include <hip/hip_runtime.h>
#include <hip/hip_bf16.h>

// ---------------- problem constants ----------------
#define B_TOTAL   32768
#define L_SITES   256
#define N_MID     254        // L-2 middle sites
#define HALF_PI_F 1.57079632679489662f
#define EPS_NORM  1e-8f

// ---------------- ws layout (float/dword slots) ----------------
// [WS_FRAG .. +520191]  B-fragment table: 254 steps x 8 frags x 64 lanes x 4 dwords
//                       frag q = h*4 + kh*2 + p  (h: n-half, kh: k-half/feature, p: 0=hi,1=lo)
// [WS_C0   .. +63]      core0 fp32  [f][32]
// [WS_CN   .. +639]     coreN fp32  [f][a][10]
// [WS_X    .. +8388607] xT fp32 [L][B]  (transposed)
// [WS_FLAG]             u32 flag: 1 = inputs are bf16, 0 = fp32
#define WS_FRAG 0
#define WS_C0   520192
#define WS_CN   520256
#define WS_X    520896
#define WS_FLAG 8909504

typedef short bf16x8 __attribute__((ext_vector_type(8)));
typedef float f32x4  __attribute__((ext_vector_type(4)));

__device__ __forceinline__ unsigned short f2bf(float f) {
    unsigned u = __builtin_bit_cast(unsigned, f);
    u += 0x7FFFu + ((u >> 16) & 1u);          // RNE
    return (unsigned short)(u >> 16);
}
__device__ __forceinline__ float bf2f(unsigned short h) {
    unsigned u = ((unsigned)h) << 16;
    return __builtin_bit_cast(float, u);
}
__device__ __forceinline__ bf16x8 asbf(uint4 u) {
    return __builtin_bit_cast(bf16x8, u);
}
// packed RNE f32x2 -> bf16x2 (lowers to v_cvt_pk_bf16_f32); memcpy because
// __hip_bfloat162 is not trivially copyable for __builtin_bit_cast
__device__ __forceinline__ unsigned pkbf2(float a, float b) {
    float2 p; p.x = a; p.y = b;
    __hip_bfloat162 h2 = __float22bfloat162_rn(p);
    unsigned u;
    __builtin_memcpy(&u, &h2, 4);
    return u;                                  // a in bits 0..15, b in 16..31
}
// split 8 fp32 into hi/lo bf16 fragments via packed cvt (same RNE math as the
// scalar split8 proven in rounds 2/7 — exonerated for correctness by r4-vs-r5/6)
__device__ __forceinline__ void split8(const float* v, bf16x8& hi, bf16x8& lo) {
    uint4 H, L;
    unsigned* hp = (unsigned*)&H;
    unsigned* lp = (unsigned*)&L;
    #pragma unroll
    for (int d = 0; d < 4; ++d) {
        float a = v[2 * d], b = v[2 * d + 1];
        unsigned hb = pkbf2(a, b);
        float h0 = __builtin_bit_cast(float, hb << 16);
        float h1 = __builtin_bit_cast(float, hb & 0xFFFF0000u);
        hp[d] = hb;
        lp[d] = pkbf2(a - h0, b - h1);         // exact residuals
    }
    hi = __builtin_bit_cast(bf16x8, H);
    lo = __builtin_bit_cast(bf16x8, L);
}
// per-wave input-dtype flag: bf16 pairs always have low16 < 0x4000
__device__ __forceinline__ bool detect_bf16(const unsigned* x_raw, int lane) {
    unsigned v = x_raw[lane];
    return __ballot((v & 0xFFFFu) >= 0x4000u) == 0ull;
}

// ---------------- fused aux kernel (round-5 structure, exonerated) ----------------
// blocks [0,2048)   : x transpose [B][L] -> xT [L][B] fp32
// blocks [2048,2556): B-fragment builder
// block  2556       : small cores -> fp32, + WS_FLAG write
__global__ __launch_bounds__(256)
void aux_all(const void* __restrict__ x_in, const void* __restrict__ c0_in,
             const void* __restrict__ am_in, const void* __restrict__ cn_in,
             float* __restrict__ ws) {
    const int lane = threadIdx.x & 63;
    const bool bf = detect_bf16((const unsigned*)x_in, lane);
    const int b = blockIdx.x;

    if (b < 2048) {
        __shared__ float tile[64][65];
        const int bb = (b & 511) * 64;
        const int ll = (b >> 9) * 64;
        #pragma unroll
        for (int k = 0; k < 16; ++k) {
            int idx = threadIdx.x + k * 256;
            int row = idx >> 6, col = idx & 63;
            size_t gi = (size_t)(bb + row) * L_SITES + ll + col;
            float v = bf ? bf2f(((const unsigned short*)x_in)[gi])
                         : ((const float*)x_in)[gi];
            tile[row][col] = v;
        }
        __syncthreads();
        #pragma unroll
        for (int k = 0; k < 16; ++k) {
            int idx = threadIdx.x + k * 256;
            int row = idx >> 6, col = idx & 63;
            ws[WS_X + (size_t)(ll + row) * B_TOTAL + bb + col] = tile[col][row];
        }
    } else if (b < 2556) {
        int i = (b - 2048) * 256 + threadIdx.x;
        if (i < N_MID * 8 * 64) {
            const int l  = i & 63;
            const int q  = (i >> 6) & 7;
            const int t  = i >> 9;
            const int h  = q >> 2;
            const int kh = (q >> 1) & 1;
            const int p  = q & 1;
            const int n  = h * 16 + (l & 15);
            const int kb = (l >> 4) * 8;
            unsigned dw[4];
            #pragma unroll
            for (int d = 0; d < 4; ++d) {
                unsigned e01[2];
                #pragma unroll
                for (int s = 0; s < 2; ++s) {
                    int a = kb + 2 * d + s;
                    size_t idx = ((size_t)(t * 2 + kh) * 32 + a) * 32 + n;
                    float v = bf ? bf2f(((const unsigned short*)am_in)[idx])
                                 : ((const float*)am_in)[idx];
                    unsigned short hi = f2bf(v);
                    e01[s] = (p == 0) ? hi : f2bf(v - bf2f(hi));
                }
                dw[d] = e01[0] | (e01[1] << 16);
            }
            uint4 o; o.x = dw[0]; o.y = dw[1]; o.z = dw[2]; o.w = dw[3];
            ((uint4*)ws)[(size_t)(t * 8 + q) * 64 + l] = o;
        }
    } else {
        for (int i = threadIdx.x; i < 640; i += 256) {
            if (i < 64)
                ws[WS_C0 + i] = bf ? bf2f(((const unsigned short*)c0_in)[i])
                                   : ((const float*)c0_in)[i];
            ws[WS_CN + i] = bf ? bf2f(((const unsigned short*)cn_in)[i])
                               : ((const float*)cn_in)[i];
        }
        if (threadIdx.x == 0)
            *(unsigned*)(ws + WS_FLAG) = bf ? 1u : 0u;
    }
}

// ---------------- main chain kernel ----------------
// Round-7-proven structure: scaled stacks [ct*M ; st*M] @ [A0;A1] via two
// 3xBF16 splits (NO fold-after — empirically cursed, rounds 4-6).
// Deltas this round: packed split8 (v_cvt_pk_bf16_f32), deferred normalization
// (every 8th step + final; chain is scale-invariant in between).
__global__ __launch_bounds__(256)
void mps_mfma(const float* __restrict__ ws, void* __restrict__ out) {
    __shared__ float T[4][528];                 // per-wave 16 rows x stride 33
    const int lane = threadIdx.x & 63;
    const int w    = threadIdx.x >> 6;
    const int r    = lane & 15;
    const int quad = lane >> 4;
    const int b0   = (blockIdx.x * 4 + w) * 16;
    const float* __restrict__ xT = ws + WS_X;
    const uint4* __restrict__ BF = (const uint4*)ws;   // WS_FRAG = 0
    float* __restrict__ Tw = &T[w][0];

    // ---- M0 in row-major k-slice order (not normalized, per reference) ----
    float mm[8];
    {
        float x0 = xT[b0 + r];
        float sn, cs; __sincosf(HALF_PI_F * x0, &sn, &cs);
        const float* c0 = ws + WS_C0;
        #pragma unroll
        for (int j = 0; j < 8; ++j) {
            int a = quad * 8 + j;
            mm[j] = cs * c0[a] + sn * c0[32 + a];
        }
    }

    #pragma unroll 1
    for (int t = 0; t < N_MID; ++t) {
        const uint4* Bt = BF + (size_t)(t * 8) * 64 + lane;
        uint4 q0 = Bt[0];        // h=0 kh=0 hi
        uint4 q1 = Bt[64];       // h=0 kh=0 lo
        uint4 q2 = Bt[128];      // h=0 kh=1 hi
        uint4 q3 = Bt[192];      // h=0 kh=1 lo
        uint4 q4 = Bt[256];      // h=1 kh=0 hi
        uint4 q5 = Bt[320];      // h=1 kh=0 lo
        uint4 q6 = Bt[384];      // h=1 kh=1 hi
        uint4 q7 = Bt[448];      // h=1 kh=1 lo

        float xt = xT[(size_t)(1 + t) * B_TOTAL + b0 + r];
        float st, ct; __sincosf(HALF_PI_F * xt, &st, &ct);

        // scaled stacked A-operand rows: [ct*M ; st*M]  (two splits — proven)
        float s0[8], s1[8];
        #pragma unroll
        for (int j = 0; j < 8; ++j) { s0[j] = ct * mm[j]; s1[j] = st * mm[j]; }
        bf16x8 m0h, m0l, m1h, m1l;
        split8(s0, m0h, m0l);
        split8(s1, m1h, m1l);

        const f32x4 z = {0.f, 0.f, 0.f, 0.f};
        // 4 independent 3-chains (h x kh), then add kh-halves
        f32x4 a00 = __builtin_amdgcn_mfma_f32_16x16x32_bf16(m0h, asbf(q0), z, 0, 0, 0);
        a00 = __builtin_amdgcn_mfma_f32_16x16x32_bf16(m0l, asbf(q0), a00, 0, 0, 0);
        a00 = __builtin_amdgcn_mfma_f32_16x16x32_bf16(m0h, asbf(q1), a00, 0, 0, 0);
        f32x4 a01 = __builtin_amdgcn_mfma_f32_16x16x32_bf16(m1h, asbf(q2), z, 0, 0, 0);
        a01 = __builtin_amdgcn_mfma_f32_16x16x32_bf16(m1l, asbf(q2), a01, 0, 0, 0);
        a01 = __builtin_amdgcn_mfma_f32_16x16x32_bf16(m1h, asbf(q3), a01, 0, 0, 0);
        f32x4 a10 = __builtin_amdgcn_mfma_f32_16x16x32_bf16(m0h, asbf(q4), z, 0, 0, 0);
        a10 = __builtin_amdgcn_mfma_f32_16x16x32_bf16(m0l, asbf(q4), a10, 0, 0, 0);
        a10 = __builtin_amdgcn_mfma_f32_16x16x32_bf16(m0h, asbf(q5), a10, 0, 0, 0);
        f32x4 a11 = __builtin_amdgcn_mfma_f32_16x16x32_bf16(m1h, asbf(q6), z, 0, 0, 0);
        a11 = __builtin_amdgcn_mfma_f32_16x16x32_bf16(m1l, asbf(q6), a11, 0, 0, 0);
        a11 = __builtin_amdgcn_mfma_f32_16x16x32_bf16(m1h, asbf(q7), a11, 0, 0, 0);
        f32x4 y0 = a00 + a01;    // cols 0..15   (c = lane&15)
        f32x4 y1 = a10 + a11;    // cols 16..31

        // C-layout -> row-layout via private-wave LDS transpose (round-2 proven).
        // write: row = quad*4+reg, col = 16h + r
        #pragma unroll
        for (int reg = 0; reg < 4; ++reg) {
            Tw[(quad * 4 + reg) * 33 + r]      = y0[reg];
            Tw[(quad * 4 + reg) * 33 + 16 + r] = y1[reg];
        }
        // read: row = r, cols quad*8 + j   (2-way bank aliasing only: free)
        #pragma unroll
        for (int j = 0; j < 8; ++j)
            mm[j] = Tw[r * 33 + quad * 8 + j];

        // normalize every 8th step + the final step (scale cancels in between)
        if (((t & 7) == 7) || (t == N_MID - 1)) {
            float ss = 0.f;
            #pragma unroll
            for (int j = 0; j < 8; ++j) ss = fmaf(mm[j], mm[j], ss);
            ss += __shfl_xor(ss, 16);
            ss += __shfl_xor(ss, 32);
            float kk = 1.0f / (sqrtf(ss) + EPS_NORM);
            #pragma unroll
            for (int j = 0; j < 8; ++j) mm[j] *= kk;
        }
    }

    // ---- readout: logits[r][c] = sum_a M[r][a]*(cN*KN0[a,c] + sN*KN1[a,c]) ----
    {
        float xN = xT[(size_t)(L_SITES - 1) * B_TOTAL + b0 + r];
        float sN, cN; __sincosf(HALF_PI_F * xN, &sN, &cN);
        const float* kn = ws + WS_CN;        // [f][a][10]
        float acc[10];
        #pragma unroll
        for (int c = 0; c < 10; ++c) acc[c] = 0.f;
        #pragma unroll
        for (int j = 0; j < 8; ++j) {
            int a = quad * 8 + j;
            float Ma = mm[j];
            #pragma unroll
            for (int c = 0; c < 10; ++c) {
                float fin = cN * kn[a * 10 + c] + sN * kn[320 + a * 10 + c];
                acc[c] = fmaf(Ma, fin, acc[c]);
            }
        }
        #pragma unroll
        for (int c = 0; c < 10; ++c) {
            acc[c] += __shfl_xor(acc[c], 16);
            acc[c] += __shfl_xor(acc[c], 32);
        }
        const unsigned bf = *(const unsigned*)(ws + WS_FLAG);
        if (quad == 0) {
            if (bf) {
                __hip_bfloat16* o = (__hip_bfloat16*)out;
                #pragma unroll
                for (int c = 0; c < 10; ++c)
                    o[(size_t)(b0 + r) * 10 + c] = __float2bfloat16(acc[c]);
            } else {
                float* o = (float*)out;
                #pragma unroll
                for (int c = 0; c < 10; ++c)
                    o[(size_t)(b0 + r) * 10 + c] = acc[c];
            }
        }
    }
}

// ---------------- launch ----------------
extern "C" void kernel_launch(void* const* d_in, const int* in_sizes, int n_in,
                              void* d_out, int out_size, void* d_ws, size_t ws_size,
                              hipStream_t stream) {
    float* ws = (float*)d_ws;
    aux_all<<<2557, 256, 0, stream>>>(d_in[0], d_in[1], d_in[2], d_in[3], ws);
    // 512 blocks x 4 waves x 16 samples = 32768 samples; 2048 waves = 2 waves/SIMD
    mps_mfma<<<512, 256, 0, stream>>>(ws, d_out);
}